// Round 16
// baseline (191.143 us; speedup 1.0000x reference)
//
#include <hip/hip_runtime.h>
#include <hip/hip_bf16.h>

#define M_ 501
#define T_ 512
#define DT_ 0.01f

typedef __attribute__((ext_vector_type(8))) __bf16 bf16x8;
typedef __attribute__((ext_vector_type(4))) float f32x4;

static __device__ __forceinline__ unsigned int pack2(float a, float b) {
    __hip_bfloat16 ha = __float2bfloat16(a);
    __hip_bfloat16 hb = __float2bfloat16(b);
    unsigned short ua = __builtin_bit_cast(unsigned short, ha);
    unsigned short ub = __builtin_bit_cast(unsigned short, hb);
    return (unsigned int)ua | ((unsigned int)ub << 16);
}
static __device__ __forceinline__ f32x4 ldu4(const float* p) {  // 4B-aligned ok
    f32x4 v; __builtin_memcpy(&v, p, 16); return v;
}
static __device__ __forceinline__ bf16x8 to_bf8(float f0, float f1, float f2, float f3,
                                                float f4, float f5, float f6, float f7) {
    uint4 vv;
    vv.x = pack2(f0, f1); vv.y = pack2(f2, f3);
    vv.z = pack2(f4, f5); vv.w = pack2(f6, f7);
    return __builtin_bit_cast(bf16x8, vv);
}

// ---------------- P2: W1comb (1024 x 384) pre-swizzled into MFMA fragment order
// [((kg*24 + nt)*64 + lane)*8 + e] : k = kg*32 + (lane>>4)*8 + e, n = nt*16 + (lane&15)
__global__ void build_w(const float* __restrict__ Ew1, const float* __restrict__ bw1,
                        const float* __restrict__ nw1, __hip_bfloat16* __restrict__ Wswz) {
    int idx = blockIdx.x * 256 + threadIdx.x;       // total 32*24*64*8 = 393216
    if (idx >= 32 * 24 * 64 * 8) return;
    int e  = idx & 7;
    int l  = (idx >> 3) & 63;
    int t  = idx >> 9;
    int nt = t % 24, k0 = t / 24;
    int k  = k0 * 32 + ((l >> 4) << 3) + e;
    int n  = nt * 16 + (l & 15);
    float v = 0.f;
    if (n < 128)      { if (k < 2*M_)             v = Ew1[k * 128 + n]; }
    else if (n < 256) { if (k < 2*M_)             v = bw1[k * 128 + (n - 128)]; }
    else              { if (k >= M_ && k < 2*M_)  v = nw1[(k - M_) * 128 + (n - 256)]; }
    Wswz[idx] = __float2bfloat16(v);
}

// ---------------- Fused: direct-from-global GEMM (no LDS-X, no staging, no
// k-loop barriers) + epilogue + scan. 512 thr (8 waves), 64 rows/block.
// A-fragment: lane (c,g) reads rows brow+mi*16+c at col kg*32+g*8 — each load
// instruction covers 16 rows x 64B fully-used lines; all 8 waves share the
// same 8KB/kg A-window (L1 hits) and the 24KB/kg W window. f32 -> bf16 in
// registers (4 pack2/frag). Boundary kgs 15/31 use clamped scalar loads.
__global__ __launch_bounds__(512, 2) void fused_all(
    const float* __restrict__ E, const float* __restrict__ nu,
    const __hip_bfloat16* __restrict__ Wswz,
    const float* __restrict__ Eb1, const float* __restrict__ bb1, const float* __restrict__ nb1,
    const float* __restrict__ Ew2, const float* __restrict__ bw2, const float* __restrict__ nw2,
    const float* __restrict__ Eb2, const float* __restrict__ bb2, const float* __restrict__ nb2,
    const float* __restrict__ e, const float* __restrict__ ed,
    float* __restrict__ stress, float* __restrict__ xiout, int B)
{
    const int tid = threadIdx.x;
    const int wid = tid >> 6, l = tid & 63;
    const int c = l & 15, g = l >> 4;
    const int brow = blockIdx.x * 64;

    __shared__ float cb1[384], cw2[384];
    __shared__ float lds_s[3][64];

    if (tid < 384) {
        int n = tid;
        cb1[n] = (n < 128) ? Eb1[n] : (n < 256) ? bb1[n - 128] : nb1[n - 256];
        cw2[n] = (n < 128) ? Ew2[n] : (n < 256) ? bw2[n - 128] : nw2[n - 256];
    }
    if (tid < 192) ((float*)lds_s)[tid] = 0.f;

    const bf16x8* wbase = (const bf16x8*)Wswz;
    const size_t lim = (size_t)B * M_;

    size_t ro[4];
    #pragma unroll
    for (int mi = 0; mi < 4; ++mi) ro[mi] = (size_t)(brow + mi * 16 + c) * M_;

    f32x4 acc[4][3];
    #pragma unroll
    for (int mi = 0; mi < 4; mi++)
        #pragma unroll
        for (int nt = 0; nt < 3; nt++) acc[mi][nt] = (f32x4){0.f, 0.f, 0.f, 0.f};

    bf16x8 w[3], af[4];
    auto loadW = [&](int kg) {
        #pragma unroll
        for (int nt = 0; nt < 3; ++nt)
            w[nt] = wbase[(size_t)(kg * 24 + wid * 3 + nt) * 64 + l];
    };
    auto M12 = [&]() {
        #pragma unroll
        for (int nt = 0; nt < 3; ++nt)
            #pragma unroll
            for (int mi = 0; mi < 4; ++mi)
                acc[mi][nt] = __builtin_amdgcn_mfma_f32_16x16x32_bf16(w[nt], af[mi], acc[mi][nt], 0, 0, 0);
    };

    // ---- region 1: kg 0..14, pure E ----
    for (int kg = 0; kg < 15; ++kg) {
        loadW(kg);
        const int koff = kg * 32 + g * 8;
        #pragma unroll
        for (int mi = 0; mi < 4; ++mi) {
            const float* p = E + ro[mi] + koff;
            f32x4 lo = ldu4(p), hi = ldu4(p + 4);
            af[mi] = to_bf8(lo[0], lo[1], lo[2], lo[3], hi[0], hi[1], hi[2], hi[3]);
        }
        M12();
    }
    // ---- kg = 15: E/nu straddle (k = 480..511), clamped scalar path ----
    {
        loadW(15);
        #pragma unroll
        for (int mi = 0; mi < 4; ++mi) {
            const size_t rb2 = ro[mi];
            const int kb = 480 + g * 8;
            auto ldx = [&](int k) -> float {
                size_t ie = rb2 + (size_t)k;
                float ve = E[ie < lim ? ie : (lim - 1)];
                float vn = nu[rb2 + (size_t)(k >= M_ ? k - M_ : 0)];
                return (k < M_) ? ve : vn;
            };
            af[mi] = to_bf8(ldx(kb+0), ldx(kb+1), ldx(kb+2), ldx(kb+3),
                            ldx(kb+4), ldx(kb+5), ldx(kb+6), ldx(kb+7));
        }
        M12();
    }
    // ---- region 2: kg 16..30, pure nu ----
    for (int kg = 16; kg < 31; ++kg) {
        loadW(kg);
        const int koff = kg * 32 - M_ + g * 8;
        #pragma unroll
        for (int mi = 0; mi < 4; ++mi) {
            const float* p = nu + ro[mi] + koff;
            f32x4 lo = ldu4(p), hi = ldu4(p + 4);
            af[mi] = to_bf8(lo[0], lo[1], lo[2], lo[3], hi[0], hi[1], hi[2], hi[3]);
        }
        M12();
    }
    // ---- kg = 31: nu tail + zero pad (k = 992..1023) ----
    {
        loadW(31);
        #pragma unroll
        for (int mi = 0; mi < 4; ++mi) {
            const size_t rb2 = ro[mi];
            const int kb = 992 + g * 8;
            auto ldx = [&](int k) -> float {
                int kn = k - M_;                      // 491..522
                size_t in_ = rb2 + (size_t)(kn <= 500 ? kn : 500);
                float vn = nu[in_];
                return (k < 2 * M_) ? vn : 0.f;
            };
            af[mi] = to_bf8(ldx(kb+0), ldx(kb+1), ldx(kb+2), ldx(kb+3),
                            ldx(kb+4), ldx(kb+5), ldx(kb+6), ldx(kb+7));
        }
        M12();
    }
    __syncthreads();                                  // lds_s/cb1/cw2 ready

    // ---- epilogue: hidden-units on reg axis -> cheap reduce ----
    float bv[12], wv[12];
    #pragma unroll
    for (int nt = 0; nt < 3; ++nt)
        #pragma unroll
        for (int r = 0; r < 4; ++r) {
            int nidx = (wid * 3 + nt) * 16 + g * 4 + r;
            bv[nt * 4 + r] = cb1[nidx];
            wv[nt * 4 + r] = cw2[nidx];
        }
    const int m_first = (wid * 3) >> 3, m_last = (wid * 3 + 2) >> 3;

    #pragma unroll
    for (int mi = 0; mi < 4; ++mi) {
        float s0 = 0.f, s1 = 0.f, s2 = 0.f;
        #pragma unroll
        for (int nt = 0; nt < 3; ++nt) {
            float p = 0.f;
            #pragma unroll
            for (int r = 0; r < 4; ++r) {
                float x = acc[mi][nt][r] + bv[nt * 4 + r];
                float h = fmaxf(x, 0.f) + __logf(1.f + __expf(-fabsf(x)));
                p += h * wv[nt * 4 + r];
            }
            int m = (wid * 3 + nt) >> 3;
            if (m == 0) s0 += p; else if (m == 1) s1 += p; else s2 += p;
        }
        auto red = [&](float v, int m) {
            v += __shfl_xor(v, 16);
            v += __shfl_xor(v, 32);
            if (l < 16) atomicAdd(&lds_s[m][mi * 16 + l], v);
        };
        if (m_first == 0) red(s0, 0);
        if (m_first <= 1 && m_last >= 1) red(s1, 1);
        if (m_last == 2) red(s2, 2);
    }
    __syncthreads();

    // ---- finalize per-row scalars in LDS ----
    if (tid < 64) {
        float s0 = lds_s[0][tid], s1 = lds_s[1][tid], s2 = lds_s[2][tid];
        lds_s[0][tid] = __expf(s0 + Eb2[0]);                      // Emod
        float mb = s1 + bb2[0];
        lds_s[1][tid] = mb * mb * (1.f / 40000.f);                // beta
        float mn = s2 + nb2[0];
        lds_s[2][tid] = __expf(mn * mn * (1.f / 40000.f));        // nuv
    }
    __syncthreads();

    // ---- fused scan: wave wid handles rows wid*8 .. wid*8+7 ----
    for (int i = 0; i < 8; ++i) {
        const int rr = wid * 8 + i;
        const int b = brow + rr;
        float Em = lds_s[0][rr], bt = lds_s[1][rr], nv = lds_s[2][rr];
        float cc = DT_ * bt;
        float a  = 1.f - cc;

        size_t base = (size_t)b * T_ + (size_t)l * 8;
        float4 e0 = *(const float4*)(e + base),  e1 = *(const float4*)(e + base + 4);
        float4 d0 = *(const float4*)(ed + base), d1 = *(const float4*)(ed + base + 4);
        float ev[8] = {e0.x, e0.y, e0.z, e0.w, e1.x, e1.y, e1.z, e1.w};
        float dv[8] = {d0.x, d0.y, d0.z, d0.w, d1.x, d1.y, d1.z, d1.w};

        float S = 0.f;
        #pragma unroll
        for (int j = 0; j < 8; j++) S = a * S + ev[j];
        float a2 = a * a, a4 = a2 * a2, A = a4 * a4;

        #pragma unroll
        for (int d = 1; d < 64; d <<= 1) {
            float Su = __shfl_up(S, d);
            float Au = __shfl_up(A, d);
            if (l >= d) { S = Su * A + S; A = Au * A; }
        }
        float Sp = __shfl_up(S, 1);
        float xi = (l == 0) ? 0.f : cc * Sp;

        float st[8], xo[8];
        #pragma unroll
        for (int j = 0; j < 8; j++) {
            xo[j] = xi;
            float qd = ev[j] - xi;
            st[j] = Em * ev[j] + qd + nv * dv[j];
            xi = xi + cc * qd;
        }
        *(float4*)(stress + base)     = (float4){st[0], st[1], st[2], st[3]};
        *(float4*)(stress + base + 4) = (float4){st[4], st[5], st[6], st[7]};
        *(float4*)(xiout + base)      = (float4){xo[0], xo[1], xo[2], xo[3]};
        *(float4*)(xiout + base + 4)  = (float4){xo[4], xo[5], xo[6], xo[7]};
    }
}

extern "C" void kernel_launch(void* const* d_in, const int* in_sizes, int n_in,
                              void* d_out, int out_size, void* d_ws, size_t ws_size,
                              hipStream_t stream) {
    const float* e   = (const float*)d_in[0];
    const float* ed  = (const float*)d_in[1];
    const float* E   = (const float*)d_in[2];
    const float* nu  = (const float*)d_in[3];
    const float* Ew1 = (const float*)d_in[4];
    const float* Eb1 = (const float*)d_in[5];
    const float* Ew2 = (const float*)d_in[6];
    const float* Eb2 = (const float*)d_in[7];
    const float* nw1 = (const float*)d_in[8];
    const float* nb1 = (const float*)d_in[9];
    const float* nw2 = (const float*)d_in[10];
    const float* nb2 = (const float*)d_in[11];
    const float* bw1 = (const float*)d_in[12];
    const float* bb1 = (const float*)d_in[13];
    const float* bw2 = (const float*)d_in[14];
    const float* bb2 = (const float*)d_in[15];

    int B = in_sizes[2] / M_;                       // 32768

    char* ws = (char*)d_ws;
    __hip_bfloat16* Wswz = (__hip_bfloat16*)ws;     // 786432 bytes

    float* stress = (float*)d_out;
    float* xiout  = stress + (size_t)B * T_;

    build_w<<<(1024 * 384 + 255) / 256, 256, 0, stream>>>(Ew1, bw1, nw1, Wswz);
    fused_all<<<B / 64, 512, 0, stream>>>(E, nu, Wswz, Eb1, bb1, nb1,
                                          Ew2, bw2, nw2, Eb2, bb2, nb2,
                                          e, ed, stress, xiout, B);
}

// Round 17
// 121.832 us; speedup vs baseline: 1.5689x; 1.5689x over previous
//
#include <hip/hip_runtime.h>
#include <hip/hip_bf16.h>

#define M_ 501
#define T_ 512
#define DT_ 0.01f

typedef __attribute__((ext_vector_type(8))) __bf16 bf16x8;
typedef __attribute__((ext_vector_type(4))) float f32x4;

static __device__ __forceinline__ unsigned int pack2(float a, float b) {
    __hip_bfloat16 ha = __float2bfloat16(a);
    __hip_bfloat16 hb = __float2bfloat16(b);
    unsigned short ua = __builtin_bit_cast(unsigned short, ha);
    unsigned short ub = __builtin_bit_cast(unsigned short, hb);
    return (unsigned int)ua | ((unsigned int)ub << 16);
}

// ---------------- P2: W1comb (1024 x 384) pre-swizzled into MFMA fragment order
__global__ void build_w(const float* __restrict__ Ew1, const float* __restrict__ bw1,
                        const float* __restrict__ nw1, __hip_bfloat16* __restrict__ Wswz) {
    int idx = blockIdx.x * 256 + threadIdx.x;       // total 32*24*64*8 = 393216
    if (idx >= 32 * 24 * 64 * 8) return;
    int e  = idx & 7;
    int l  = (idx >> 3) & 63;
    int t  = idx >> 9;
    int nt = t % 24, k0 = t / 24;
    int k  = k0 * 32 + ((l >> 4) << 3) + e;
    int n  = nt * 16 + (l & 15);
    float v = 0.f;
    if (n < 128)      { if (k < 2*M_)             v = Ew1[k * 128 + n]; }
    else if (n < 256) { if (k < 2*M_)             v = bw1[k * 128 + (n - 128)]; }
    else              { if (k >= M_ && k < 2*M_)  v = nw1[(k - M_) * 128 + (n - 256)]; }
    Wswz[idx] = __float2bfloat16(v);
}

// ---------------- Fused: GEMM (3-ring, 2-deep stage, raw barriers, NO
// sched_barrier) + epilogue + scan(2-row pairs). 512 thr, 64 rows/block.
// BAR = lgkmcnt(0) + s_barrier only: in-flight stage VMEM crosses barriers
// (T4), giving each stage load a full chunk (~1500cy) of latency cover.
// R15 proved this protocol correct; R15's regression is attributed to its
// sched_barrier(0) order-pin (m141: -42% on such loops) — removed here.
// + T5 setprio around MFMA clusters, + bijective XCD swizzle (512 = 8*64).
__global__ __launch_bounds__(512, 2) void fused_all(
    const float* __restrict__ E, const float* __restrict__ nu,
    const __hip_bfloat16* __restrict__ Wswz,
    const float* __restrict__ Eb1, const float* __restrict__ bb1, const float* __restrict__ nb1,
    const float* __restrict__ Ew2, const float* __restrict__ bw2, const float* __restrict__ nw2,
    const float* __restrict__ Eb2, const float* __restrict__ bb2, const float* __restrict__ nb2,
    const float* __restrict__ e, const float* __restrict__ ed,
    float* __restrict__ stress, float* __restrict__ xiout, int B)
{
    const int tid = threadIdx.x;
    const int wid = tid >> 6, l = tid & 63;
    const int c = l & 15, g = l >> 4;
    const int bid = blockIdx.x;
    const int swz = (bid & 7) * 64 + (bid >> 3);     // XCD-chunked, bijective (512=8*64)
    const int brow = swz * 64;

    __shared__ __align__(16) unsigned char sAraw[3][64 * 128];    // 24 KB ring
    __shared__ float cb1[384], cw2[384];
    __shared__ float lds_s[3][64];

    if (tid < 384) {
        int n = tid;
        cb1[n] = (n < 128) ? Eb1[n] : (n < 256) ? bb1[n - 128] : nb1[n - 256];
        cw2[n] = (n < 128) ? Ew2[n] : (n < 256) ? bw2[n - 128] : nw2[n - 256];
    }
    if (tid < 192) ((float*)lds_s)[tid] = 0.f;

    // ---- staging machinery: 1 item/thread/chunk, two register sets ----
    const int sr = tid >> 3, su = tid & 7;           // row 0..63, col-octet 0..7
    const size_t rb = (size_t)(brow + sr) * M_;
    f32x4 qa0, qa1, qa2, qb0, qb1, qb2; int oa = 0, ob = 0;

    auto stage_load = [&](int ch, f32x4& r0, f32x4& r1, f32x4& r2, int& ro) {
        int cu = ch * 8 + su;
        bool slow = (cu == 62) | (cu >= 124);
        if (!slow) {
            const float* src = (cu < 62) ? E : nu;
            int off = (cu < 62) ? cu * 8 : cu * 8 - M_;
            size_t s = rb + (size_t)off;
            ro = (int)(s & 3);
            const f32x4* p = (const f32x4*)(src + (s & ~(size_t)3));
            r0 = p[0]; r1 = p[1]; r2 = p[2];
        } else {
            int kb = cu * 8;
            auto ldx = [&](int k) -> float {
                return (k < M_) ? E[rb + k] : ((k < 2 * M_) ? nu[rb + k - M_] : 0.f);
            };
            r0 = (f32x4){ldx(kb+0), ldx(kb+1), ldx(kb+2), ldx(kb+3)};
            r1 = (f32x4){ldx(kb+4), ldx(kb+5), ldx(kb+6), ldx(kb+7)};
            r2 = (f32x4){0.f, 0.f, 0.f, 0.f};
            ro = 0;
        }
    };
    auto stage_finish = [&](int nbuf, f32x4& r0, f32x4& r1, f32x4& r2, int& ro) {
        asm volatile("" : "+v"(r0), "+v"(r1), "+v"(r2));   // first use: vmcnt wait (loads are ~1 chunk old)
        float g0=r0[0], g1=r0[1], g2=r0[2], g3=r0[3],
              g4=r1[0], g5=r1[1], g6=r1[2], g7=r1[3],
              g8=r2[0], g9=r2[1], g10=r2[2];
        const bool o2 = (ro & 2) != 0, o1 = (ro & 1) != 0;
        float u0 = o2?g2:g0, u1 = o2?g3:g1, u2 = o2?g4:g2, u3 = o2?g5:g3,
              u4 = o2?g6:g4, u5 = o2?g7:g5, u6 = o2?g8:g6, u7 = o2?g9:g7,
              u8 = o2?g10:g8;
        float f0 = o1?u1:u0, f1 = o1?u2:u1, f2 = o1?u3:u2, f3 = o1?u4:u3,
              f4 = o1?u5:u4, f5 = o1?u6:u5, f6 = o1?u7:u6, f7 = o1?u8:u7;
        uint4 vv;
        vv.x = pack2(f0, f1); vv.y = pack2(f2, f3);
        vv.z = pack2(f4, f5); vv.w = pack2(f6, f7);
        unsigned bo = ((unsigned)sr << 7) + ((((unsigned)su) << 4) ^ (((unsigned)(sr & 7)) << 4));
        *(uint4*)(sAraw[nbuf] + bo) = vv;
    };

    const bf16x8* wbase = (const bf16x8*)Wswz;

    f32x4 acc[4][3];
    #pragma unroll
    for (int mi = 0; mi < 4; mi++)
        #pragma unroll
        for (int nt = 0; nt < 3; nt++) acc[mi][nt] = (f32x4){0.f, 0.f, 0.f, 0.f};

    auto compute = [&](int bufi, int ch) {
        #pragma unroll
        for (int kk = 0; kk < 2; ++kk) {
            const int kg = ch * 2 + kk;
            bf16x8 w[3];
            #pragma unroll
            for (int nt = 0; nt < 3; ++nt)
                w[nt] = wbase[(size_t)(kg * 24 + wid * 3 + nt) * 64 + l];
            bf16x8 af[4];
            #pragma unroll
            for (int mi = 0; mi < 4; ++mi) {
                int row = c + mi * 16;
                unsigned bo = ((unsigned)row << 7) +
                    ((((unsigned)kk << 6) + ((unsigned)g << 4)) ^ (((unsigned)(row & 7)) << 4));
                af[mi] = *(const bf16x8*)(sAraw[bufi] + bo);
            }
            __builtin_amdgcn_s_setprio(1);
            #pragma unroll
            for (int nt = 0; nt < 3; ++nt)
                #pragma unroll
                for (int mi = 0; mi < 4; ++mi)
                    acc[mi][nt] = __builtin_amdgcn_mfma_f32_16x16x32_bf16(w[nt], af[mi], acc[mi][nt], 0, 0, 0);
            __builtin_amdgcn_s_setprio(0);
        }
    };

    #define BAR() do {                                        \
        asm volatile("s_waitcnt lgkmcnt(0)" ::: "memory");    \
        __builtin_amdgcn_s_barrier();                         \
    } while (0)

    // ---- prologue: fill buf0, buf1; stage(2) left in flight in qa ----
    stage_load(0, qa0, qa1, qa2, oa);
    stage_load(1, qb0, qb1, qb2, ob);
    stage_finish(0, qa0, qa1, qa2, oa);
    stage_load(2, qa0, qa1, qa2, oa);
    stage_finish(1, qb0, qb1, qb2, ob);
    BAR();

    // ---- chunk loop: q[parity] holds stage(ch+2), loads stay in flight over BAR
    for (int ch = 0; ch < 16; ch += 2) {
        compute(ch % 3, ch);
        if (ch + 3 < 16) stage_load(ch + 3, qb0, qb1, qb2, ob);
        if (ch + 2 < 16) stage_finish((ch + 2) % 3, qa0, qa1, qa2, oa);
        BAR();
        const int c1 = ch + 1;
        compute(c1 % 3, c1);
        if (c1 + 3 < 16) stage_load(c1 + 3, qa0, qa1, qa2, oa);
        if (c1 + 2 < 16) stage_finish((c1 + 2) % 3, qb0, qb1, qb2, ob);
        BAR();
    }
    #undef BAR

    // ---- epilogue: hidden-units on reg axis -> cheap reduce ----
    float bv[12], wv[12];
    #pragma unroll
    for (int nt = 0; nt < 3; ++nt)
        #pragma unroll
        for (int r = 0; r < 4; ++r) {
            int nidx = (wid * 3 + nt) * 16 + g * 4 + r;
            bv[nt * 4 + r] = cb1[nidx];
            wv[nt * 4 + r] = cw2[nidx];
        }
    const int m_first = (wid * 3) >> 3, m_last = (wid * 3 + 2) >> 3;

    #pragma unroll
    for (int mi = 0; mi < 4; ++mi) {
        float s0 = 0.f, s1 = 0.f, s2 = 0.f;
        #pragma unroll
        for (int nt = 0; nt < 3; ++nt) {
            float p = 0.f;
            #pragma unroll
            for (int r = 0; r < 4; ++r) {
                float x = acc[mi][nt][r] + bv[nt * 4 + r];
                float h = fmaxf(x, 0.f) + __logf(1.f + __expf(-fabsf(x)));
                p += h * wv[nt * 4 + r];
            }
            int m = (wid * 3 + nt) >> 3;
            if (m == 0) s0 += p; else if (m == 1) s1 += p; else s2 += p;
        }
        auto red = [&](float v, int m) {
            v += __shfl_xor(v, 16);
            v += __shfl_xor(v, 32);
            if (l < 16) atomicAdd(&lds_s[m][mi * 16 + l], v);
        };
        if (m_first == 0) red(s0, 0);
        if (m_first <= 1 && m_last >= 1) red(s1, 1);
        if (m_last == 2) red(s2, 2);
    }
    __syncthreads();

    if (tid < 64) {
        float s0 = lds_s[0][tid], s1 = lds_s[1][tid], s2 = lds_s[2][tid];
        lds_s[0][tid] = __expf(s0 + Eb2[0]);                      // Emod
        float mb = s1 + bb2[0];
        lds_s[1][tid] = mb * mb * (1.f / 40000.f);                // beta
        float mn = s2 + nb2[0];
        lds_s[2][tid] = __expf(mn * mn * (1.f / 40000.f));        // nuv
    }
    __syncthreads();

    // ---- fused scan: 2-row pairs (independent chains interleave) ----
    #pragma unroll
    for (int pi = 0; pi < 4; ++pi) {
        const int rA = wid * 8 + pi * 2, rB = rA + 1;
        const int bA = brow + rA, bB = brow + rB;
        float EmA = lds_s[0][rA], btA = lds_s[1][rA], nvA = lds_s[2][rA];
        float EmB = lds_s[0][rB], btB = lds_s[1][rB], nvB = lds_s[2][rB];
        float ccA = DT_ * btA, aA = 1.f - ccA;
        float ccB = DT_ * btB, aB = 1.f - ccB;

        size_t baA = (size_t)bA * T_ + (size_t)l * 8;
        size_t baB = (size_t)bB * T_ + (size_t)l * 8;
        float4 eA0 = *(const float4*)(e + baA),  eA1 = *(const float4*)(e + baA + 4);
        float4 eB0 = *(const float4*)(e + baB),  eB1 = *(const float4*)(e + baB + 4);
        float4 dA0 = *(const float4*)(ed + baA), dA1 = *(const float4*)(ed + baA + 4);
        float4 dB0 = *(const float4*)(ed + baB), dB1 = *(const float4*)(ed + baB + 4);
        float evA[8] = {eA0.x,eA0.y,eA0.z,eA0.w, eA1.x,eA1.y,eA1.z,eA1.w};
        float evB[8] = {eB0.x,eB0.y,eB0.z,eB0.w, eB1.x,eB1.y,eB1.z,eB1.w};
        float dvA[8] = {dA0.x,dA0.y,dA0.z,dA0.w, dA1.x,dA1.y,dA1.z,dA1.w};
        float dvB[8] = {dB0.x,dB0.y,dB0.z,dB0.w, dB1.x,dB1.y,dB1.z,dB1.w};

        float SA = 0.f, SB = 0.f;
        #pragma unroll
        for (int j = 0; j < 8; j++) { SA = aA * SA + evA[j]; SB = aB * SB + evB[j]; }
        float a2A = aA*aA, AA = (a2A*a2A)*(a2A*a2A);
        float a2B = aB*aB, AB = (a2B*a2B)*(a2B*a2B);

        #pragma unroll
        for (int d = 1; d < 64; d <<= 1) {
            float SuA = __shfl_up(SA, d), AuA = __shfl_up(AA, d);
            float SuB = __shfl_up(SB, d), AuB = __shfl_up(AB, d);
            if (l >= d) { SA = SuA * AA + SA; AA = AuA * AA;
                          SB = SuB * AB + SB; AB = AuB * AB; }
        }
        float SpA = __shfl_up(SA, 1), SpB = __shfl_up(SB, 1);
        float xiA = (l == 0) ? 0.f : ccA * SpA;
        float xiB = (l == 0) ? 0.f : ccB * SpB;

        float stA[8], xoA[8], stB[8], xoB[8];
        #pragma unroll
        for (int j = 0; j < 8; j++) {
            xoA[j] = xiA; xoB[j] = xiB;
            float qA = evA[j] - xiA, qB = evB[j] - xiB;
            stA[j] = EmA * evA[j] + qA + nvA * dvA[j];
            stB[j] = EmB * evB[j] + qB + nvB * dvB[j];
            xiA += ccA * qA; xiB += ccB * qB;
        }
        *(float4*)(stress + baA)     = (float4){stA[0],stA[1],stA[2],stA[3]};
        *(float4*)(stress + baA + 4) = (float4){stA[4],stA[5],stA[6],stA[7]};
        *(float4*)(stress + baB)     = (float4){stB[0],stB[1],stB[2],stB[3]};
        *(float4*)(stress + baB + 4) = (float4){stB[4],stB[5],stB[6],stB[7]};
        *(float4*)(xiout + baA)      = (float4){xoA[0],xoA[1],xoA[2],xoA[3]};
        *(float4*)(xiout + baA + 4)  = (float4){xoA[4],xoA[5],xoA[6],xoA[7]};
        *(float4*)(xiout + baB)      = (float4){xoB[0],xoB[1],xoB[2],xoB[3]};
        *(float4*)(xiout + baB + 4)  = (float4){xoB[4],xoB[5],xoB[6],xoB[7]};
    }
}

extern "C" void kernel_launch(void* const* d_in, const int* in_sizes, int n_in,
                              void* d_out, int out_size, void* d_ws, size_t ws_size,
                              hipStream_t stream) {
    const float* e   = (const float*)d_in[0];
    const float* ed  = (const float*)d_in[1];
    const float* E   = (const float*)d_in[2];
    const float* nu  = (const float*)d_in[3];
    const float* Ew1 = (const float*)d_in[4];
    const float* Eb1 = (const float*)d_in[5];
    const float* Ew2 = (const float*)d_in[6];
    const float* Eb2 = (const float*)d_in[7];
    const float* nw1 = (const float*)d_in[8];
    const float* nb1 = (const float*)d_in[9];
    const float* nw2 = (const float*)d_in[10];
    const float* nb2 = (const float*)d_in[11];
    const float* bw1 = (const float*)d_in[12];
    const float* bb1 = (const float*)d_in[13];
    const float* bw2 = (const float*)d_in[14];
    const float* bb2 = (const float*)d_in[15];

    int B = in_sizes[2] / M_;                       // 32768

    char* ws = (char*)d_ws;
    __hip_bfloat16* Wswz = (__hip_bfloat16*)ws;     // 786432 bytes

    float* stress = (float*)d_out;
    float* xiout  = stress + (size_t)B * T_;

    build_w<<<(1024 * 384 + 255) / 256, 256, 0, stream>>>(Ew1, bw1, nw1, Wswz);
    fused_all<<<B / 64, 512, 0, stream>>>(E, nu, Wswz, Eb1, bb1, nb1,
                                          Ew2, bw2, nw2, Eb2, bb2, nb2,
                                          e, ed, stress, xiout, B);
}

// Round 18
// 118.877 us; speedup vs baseline: 1.6079x; 1.0249x over previous
//
#include <hip/hip_runtime.h>
#include <hip/hip_bf16.h>

#define M_ 501
#define T_ 512
#define DT_ 0.01f

typedef __attribute__((ext_vector_type(8))) __bf16 bf16x8;
typedef __attribute__((ext_vector_type(4))) float f32x4;

static __device__ __forceinline__ unsigned int pack2(float a, float b) {
    __hip_bfloat16 ha = __float2bfloat16(a);
    __hip_bfloat16 hb = __float2bfloat16(b);
    unsigned short ua = __builtin_bit_cast(unsigned short, ha);
    unsigned short ub = __builtin_bit_cast(unsigned short, hb);
    return (unsigned int)ua | ((unsigned int)ub << 16);
}
static __device__ __forceinline__ bf16x8 to_bf8(float f0, float f1, float f2, float f3,
                                                float f4, float f5, float f6, float f7) {
    uint4 vv;
    vv.x = pack2(f0, f1); vv.y = pack2(f2, f3);
    vv.z = pack2(f4, f5); vv.w = pack2(f6, f7);
    return __builtin_bit_cast(bf16x8, vv);
}
// Register-free async global->LDS (issue point is fixed: no dest reg to sink).
static __device__ __forceinline__ void gll(const float* gp, float* lp) {
    __builtin_amdgcn_global_load_lds(
        (const __attribute__((address_space(1))) unsigned int*)gp,
        (__attribute__((address_space(3))) unsigned int*)lp, 4, 0, 0);
}

// ---------------- P2: W1comb (1024 x 384) pre-swizzled into MFMA fragment order
// [((kg*24 + nt)*64 + lane)*8 + e] : k = kg*32 + (lane>>4)*8 + e, n = nt*16 + (lane&15)
__global__ void build_w(const float* __restrict__ Ew1, const float* __restrict__ bw1,
                        const float* __restrict__ nw1, __hip_bfloat16* __restrict__ Wswz) {
    int idx = blockIdx.x * 256 + threadIdx.x;       // total 32*24*64*8 = 393216
    if (idx >= 32 * 24 * 64 * 8) return;
    int e  = idx & 7;
    int l  = (idx >> 3) & 63;
    int t  = idx >> 9;
    int nt = t % 24, k0 = t / 24;
    int k  = k0 * 32 + ((l >> 4) << 3) + e;
    int n  = nt * 16 + (l & 15);
    float v = 0.f;
    if (n < 128)      { if (k < 2*M_)             v = Ew1[k * 128 + n]; }
    else if (n < 256) { if (k < 2*M_)             v = bw1[k * 128 + (n - 128)]; }
    else              { if (k >= M_ && k < 2*M_)  v = nw1[(k - M_) * 128 + (n - 256)]; }
    Wswz[idx] = __float2bfloat16(v);
}

// ---------------- Fused: GEMM with global_load_lds f32 staging + epilogue +
// scan. 512 thr (8 waves), 64 rows/block, grid 512. BK=128 (8 chunks).
// LDS sA[2][64][132] f32: +4 pad -> row stride 528B (2-way banks = free,
// 16B-aligned fragment reads). Staging: per row 2 instrs, lane i fetches
// col (seg*64+i) -> LDS base+i*4 (256B contiguous per instr, per-lane global
// addr handles E/nu straddle + zero tail, only 4B alignment needed).
// Loads are REGISTER-FREE so the compiler cannot sink them: issued at chunk
// top, drained by the __syncthreads at chunk end after ~3000cy of compute.
// f32 -> bf16 conversion happens at fragment-read time.
__global__ __launch_bounds__(512, 2) void fused_all(
    const float* __restrict__ E, const float* __restrict__ nu,
    const __hip_bfloat16* __restrict__ Wswz, const float* __restrict__ zbuf,
    const float* __restrict__ Eb1, const float* __restrict__ bb1, const float* __restrict__ nb1,
    const float* __restrict__ Ew2, const float* __restrict__ bw2, const float* __restrict__ nw2,
    const float* __restrict__ Eb2, const float* __restrict__ bb2, const float* __restrict__ nb2,
    const float* __restrict__ e, const float* __restrict__ ed,
    float* __restrict__ stress, float* __restrict__ xiout, int B)
{
    const int tid = threadIdx.x;
    const int wid = tid >> 6, l = tid & 63;
    const int c = l & 15, g = l >> 4;
    const int brow = blockIdx.x * 64;

    __shared__ __align__(16) float sA[2][64][132];   // 67584 B
    __shared__ float cb1[384], cw2[384];
    __shared__ float lds_s[3][64];

    if (tid < 384) {
        int n = tid;
        cb1[n] = (n < 128) ? Eb1[n] : (n < 256) ? bb1[n - 128] : nb1[n - 256];
        cw2[n] = (n < 128) ? Ew2[n] : (n < 256) ? bw2[n - 128] : nw2[n - 256];
    }
    if (tid < 192) ((float*)lds_s)[tid] = 0.f;

    // ---- staging: wave wid owns rows wid*8..wid*8+7, 2 instrs/row/chunk ----
    auto issue = [&](int ch, int nbuf) {
        const int k0 = ch * 128 + l, k1 = k0 + 64;
        const float* b0 = (k0 < M_) ? E + k0 : nu + (k0 - M_);
        const float* b1 = (k1 < M_) ? E + k1 : nu + (k1 - M_);
        const bool z0 = (k0 >= 2 * M_), z1 = (k1 >= 2 * M_);
        #pragma unroll
        for (int j = 0; j < 8; ++j) {
            const int row = wid * 8 + j;
            const size_t rb2 = (size_t)(brow + row) * M_;
            const float* a0 = z0 ? (zbuf + (k0 - 2 * M_)) : (b0 + rb2);
            const float* a1 = z1 ? (zbuf + (k1 - 2 * M_)) : (b1 + rb2);
            gll(a0, &sA[nbuf][row][0]);
            gll(a1, &sA[nbuf][row][64]);
        }
    };

    const bf16x8* wbase = (const bf16x8*)Wswz;

    f32x4 acc[4][3];
    #pragma unroll
    for (int mi = 0; mi < 4; mi++)
        #pragma unroll
        for (int nt = 0; nt < 3; nt++) acc[mi][nt] = (f32x4){0.f, 0.f, 0.f, 0.f};

    auto compute = [&](int buf, int ch) {
        #pragma unroll
        for (int kgl = 0; kgl < 4; ++kgl) {
            const int kg = ch * 4 + kgl;
            bf16x8 w[3];
            #pragma unroll
            for (int nt = 0; nt < 3; ++nt)
                w[nt] = wbase[(size_t)(kg * 24 + wid * 3 + nt) * 64 + l];
            bf16x8 af[4];
            #pragma unroll
            for (int mi = 0; mi < 4; ++mi) {
                const int row = c + mi * 16;
                const float* lp = &sA[buf][row][kgl * 32 + g * 8];
                f32x4 lo = *(const f32x4*)lp;
                f32x4 hi = *(const f32x4*)(lp + 4);
                af[mi] = to_bf8(lo[0], lo[1], lo[2], lo[3], hi[0], hi[1], hi[2], hi[3]);
            }
            #pragma unroll
            for (int nt = 0; nt < 3; ++nt)
                #pragma unroll
                for (int mi = 0; mi < 4; ++mi)
                    acc[mi][nt] = __builtin_amdgcn_mfma_f32_16x16x32_bf16(w[nt], af[mi], acc[mi][nt], 0, 0, 0);
        }
    };

    // ---- pipeline: issue(ch+1) at top, barrier drain covered by compute ----
    issue(0, 0);
    __syncthreads();
    for (int ch = 0; ch < 8; ++ch) {
        if (ch < 7) issue(ch + 1, (ch + 1) & 1);
        compute(ch & 1, ch);
        __syncthreads();
    }

    // ---- epilogue: hidden-units on reg axis -> cheap reduce ----
    float bv[12], wv[12];
    #pragma unroll
    for (int nt = 0; nt < 3; ++nt)
        #pragma unroll
        for (int r = 0; r < 4; ++r) {
            int nidx = (wid * 3 + nt) * 16 + g * 4 + r;
            bv[nt * 4 + r] = cb1[nidx];
            wv[nt * 4 + r] = cw2[nidx];
        }
    const int m_first = (wid * 3) >> 3, m_last = (wid * 3 + 2) >> 3;

    #pragma unroll
    for (int mi = 0; mi < 4; ++mi) {
        float s0 = 0.f, s1 = 0.f, s2 = 0.f;
        #pragma unroll
        for (int nt = 0; nt < 3; ++nt) {
            float p = 0.f;
            #pragma unroll
            for (int r = 0; r < 4; ++r) {
                float x = acc[mi][nt][r] + bv[nt * 4 + r];
                float h = fmaxf(x, 0.f) + __logf(1.f + __expf(-fabsf(x)));
                p += h * wv[nt * 4 + r];
            }
            int m = (wid * 3 + nt) >> 3;
            if (m == 0) s0 += p; else if (m == 1) s1 += p; else s2 += p;
        }
        auto red = [&](float v, int m) {
            v += __shfl_xor(v, 16);
            v += __shfl_xor(v, 32);
            if (l < 16) atomicAdd(&lds_s[m][mi * 16 + l], v);
        };
        if (m_first == 0) red(s0, 0);
        if (m_first <= 1 && m_last >= 1) red(s1, 1);
        if (m_last == 2) red(s2, 2);
    }
    __syncthreads();

    if (tid < 64) {
        float s0 = lds_s[0][tid], s1 = lds_s[1][tid], s2 = lds_s[2][tid];
        lds_s[0][tid] = __expf(s0 + Eb2[0]);                      // Emod
        float mb = s1 + bb2[0];
        lds_s[1][tid] = mb * mb * (1.f / 40000.f);                // beta
        float mn = s2 + nb2[0];
        lds_s[2][tid] = __expf(mn * mn * (1.f / 40000.f));        // nuv
    }
    __syncthreads();

    // ---- fused scan: wave wid handles rows wid*8 .. wid*8+7 ----
    for (int i = 0; i < 8; ++i) {
        const int rr = wid * 8 + i;
        const int b = brow + rr;
        float Em = lds_s[0][rr], bt = lds_s[1][rr], nv = lds_s[2][rr];
        float cc = DT_ * bt;
        float a  = 1.f - cc;

        size_t base = (size_t)b * T_ + (size_t)l * 8;
        float4 e0 = *(const float4*)(e + base),  e1 = *(const float4*)(e + base + 4);
        float4 d0 = *(const float4*)(ed + base), d1 = *(const float4*)(ed + base + 4);
        float ev[8] = {e0.x, e0.y, e0.z, e0.w, e1.x, e1.y, e1.z, e1.w};
        float dv[8] = {d0.x, d0.y, d0.z, d0.w, d1.x, d1.y, d1.z, d1.w};

        float S = 0.f;
        #pragma unroll
        for (int j = 0; j < 8; j++) S = a * S + ev[j];
        float a2 = a * a, a4 = a2 * a2, A = a4 * a4;

        #pragma unroll
        for (int d = 1; d < 64; d <<= 1) {
            float Su = __shfl_up(S, d);
            float Au = __shfl_up(A, d);
            if (l >= d) { S = Su * A + S; A = Au * A; }
        }
        float Sp = __shfl_up(S, 1);
        float xi = (l == 0) ? 0.f : cc * Sp;

        float st[8], xo[8];
        #pragma unroll
        for (int j = 0; j < 8; j++) {
            xo[j] = xi;
            float qd = ev[j] - xi;
            st[j] = Em * ev[j] + qd + nv * dv[j];
            xi = xi + cc * qd;
        }
        *(float4*)(stress + base)     = (float4){st[0], st[1], st[2], st[3]};
        *(float4*)(stress + base + 4) = (float4){st[4], st[5], st[6], st[7]};
        *(float4*)(xiout + base)      = (float4){xo[0], xo[1], xo[2], xo[3]};
        *(float4*)(xiout + base + 4)  = (float4){xo[4], xo[5], xo[6], xo[7]};
    }
}

extern "C" void kernel_launch(void* const* d_in, const int* in_sizes, int n_in,
                              void* d_out, int out_size, void* d_ws, size_t ws_size,
                              hipStream_t stream) {
    const float* e   = (const float*)d_in[0];
    const float* ed  = (const float*)d_in[1];
    const float* E   = (const float*)d_in[2];
    const float* nu  = (const float*)d_in[3];
    const float* Ew1 = (const float*)d_in[4];
    const float* Eb1 = (const float*)d_in[5];
    const float* Ew2 = (const float*)d_in[6];
    const float* Eb2 = (const float*)d_in[7];
    const float* nw1 = (const float*)d_in[8];
    const float* nb1 = (const float*)d_in[9];
    const float* nw2 = (const float*)d_in[10];
    const float* nb2 = (const float*)d_in[11];
    const float* bw1 = (const float*)d_in[12];
    const float* bb1 = (const float*)d_in[13];
    const float* bw2 = (const float*)d_in[14];
    const float* bb2 = (const float*)d_in[15];

    int B = in_sizes[2] / M_;                       // 32768

    char* ws = (char*)d_ws;
    __hip_bfloat16* Wswz = (__hip_bfloat16*)ws;     // 786432 bytes
    float* zbuf = (float*)(ws + 786432);            // 256 B zero tail
    hipMemsetAsync(zbuf, 0, 256, stream);

    float* stress = (float*)d_out;
    float* xiout  = stress + (size_t)B * T_;

    build_w<<<(1024 * 384 + 255) / 256, 256, 0, stream>>>(Ew1, bw1, nw1, Wswz);
    fused_all<<<B / 64, 512, 0, stream>>>(E, nu, Wswz, zbuf, Eb1, bb1, nb1,
                                          Ew2, bw2, nw2, Eb2, bb2, nb2,
                                          e, ed, stress, xiout, B);
}

// Round 19
// 111.096 us; speedup vs baseline: 1.7205x; 1.0700x over previous
//
#include <hip/hip_runtime.h>
#include <hip/hip_bf16.h>

#define M_ 501
#define T_ 512
#define DT_ 0.01f

typedef __attribute__((ext_vector_type(8))) __bf16 bf16x8;
typedef __attribute__((ext_vector_type(4))) float f32x4;

static __device__ __forceinline__ unsigned int pack2(float a, float b) {
    __hip_bfloat16 ha = __float2bfloat16(a);
    __hip_bfloat16 hb = __float2bfloat16(b);
    unsigned short ua = __builtin_bit_cast(unsigned short, ha);
    unsigned short ub = __builtin_bit_cast(unsigned short, hb);
    return (unsigned int)ua | ((unsigned int)ub << 16);
}

// ---------------- P2: W1comb (1024 x 384) pre-swizzled into MFMA fragment order
// [((kg*24 + nt)*64 + lane)*8 + e] : k = kg*32 + (lane>>4)*8 + e, n = nt*16 + (lane&15)
__global__ void build_w(const float* __restrict__ Ew1, const float* __restrict__ bw1,
                        const float* __restrict__ nw1, __hip_bfloat16* __restrict__ Wswz) {
    int idx = blockIdx.x * 256 + threadIdx.x;       // total 32*24*64*8 = 393216
    if (idx >= 32 * 24 * 64 * 8) return;
    int e  = idx & 7;
    int l  = (idx >> 3) & 63;
    int t  = idx >> 9;
    int nt = t % 24, k0 = t / 24;
    int k  = k0 * 32 + ((l >> 4) << 3) + e;
    int n  = nt * 16 + (l & 15);
    float v = 0.f;
    if (n < 128)      { if (k < 2*M_)             v = Ew1[k * 128 + n]; }
    else if (n < 256) { if (k < 2*M_)             v = bw1[k * 128 + (n - 128)]; }
    else              { if (k >= M_ && k < 2*M_)  v = nw1[(k - M_) * 128 + (n - 256)]; }
    Wswz[idx] = __float2bfloat16(v);
}

// ---------------- Fused: R13 structure (best known: 110.9us) + 3 validated
// techniques: (1) bijective XCD swizzle, (2) setprio around MFMA clusters,
// (3) 2-row-paired scan. No structural changes.
__global__ __launch_bounds__(512, 4) void fused_all(
    const float* __restrict__ E, const float* __restrict__ nu,
    const __hip_bfloat16* __restrict__ Wswz,
    const float* __restrict__ Eb1, const float* __restrict__ bb1, const float* __restrict__ nb1,
    const float* __restrict__ Ew2, const float* __restrict__ bw2, const float* __restrict__ nw2,
    const float* __restrict__ Eb2, const float* __restrict__ bb2, const float* __restrict__ nb2,
    const float* __restrict__ e, const float* __restrict__ ed,
    float* __restrict__ stress, float* __restrict__ xiout, int B)
{
    const int tid = threadIdx.x;
    const int wid = tid >> 6, l = tid & 63;
    const int c = l & 15, g = l >> 4;
    const int bid = blockIdx.x;
    const int swz = (bid & 7) * 64 + (bid >> 3);     // XCD-chunked, bijective (512 = 8*64)
    const int brow = swz * 64;

    __shared__ __align__(16) unsigned char sAraw[2][64 * 128];    // 16 KB
    __shared__ float cb1[384], cw2[384];
    __shared__ float lds_s[3][64];

    if (tid < 384) {
        int n = tid;
        cb1[n] = (n < 128) ? Eb1[n] : (n < 256) ? bb1[n - 128] : nb1[n - 256];
        cw2[n] = (n < 128) ? Ew2[n] : (n < 256) ? bw2[n - 128] : nw2[n - 256];
    }
    if (tid < 192) ((float*)lds_s)[tid] = 0.f;

    // ---- staging machinery: 1 item/thread/chunk (8 elems) ----
    f32x4 q0, q1, q2; int ofs;
    const int sr = tid >> 3, su = tid & 7;           // row 0..63, col-octet 0..7
    const size_t rb = (size_t)(brow + sr) * M_;
    auto stage_load = [&](int ch) {
        int cu = ch * 8 + su;
        bool slow = (cu == 62) | (cu >= 124);
        if (!slow) {
            const float* src = (cu < 62) ? E : nu;
            int off = (cu < 62) ? cu * 8 : cu * 8 - M_;
            size_t s = rb + (size_t)off;
            ofs = (int)(s & 3);
            const f32x4* p = (const f32x4*)(src + (s & ~(size_t)3));
            q0 = p[0]; q1 = p[1]; q2 = p[2];
        } else {
            int kb = cu * 8;
            auto ldx = [&](int k) -> float {
                return (k < M_) ? E[rb + k] : ((k < 2 * M_) ? nu[rb + k - M_] : 0.f);
            };
            q0 = (f32x4){ldx(kb+0), ldx(kb+1), ldx(kb+2), ldx(kb+3)};
            q1 = (f32x4){ldx(kb+4), ldx(kb+5), ldx(kb+6), ldx(kb+7)};
            q2 = (f32x4){0.f, 0.f, 0.f, 0.f};
            ofs = 0;
        }
    };
    auto stage_finish = [&](int nbuf) {
        asm volatile("" : "+v"(q0), "+v"(q1), "+v"(q2));   // first use: wait lands here
        float g0=q0[0], g1=q0[1], g2=q0[2], g3=q0[3],
              g4=q1[0], g5=q1[1], g6=q1[2], g7=q1[3],
              g8=q2[0], g9=q2[1], g10=q2[2];
        const bool o2 = (ofs & 2) != 0, o1 = (ofs & 1) != 0;
        float u0 = o2?g2:g0, u1 = o2?g3:g1, u2 = o2?g4:g2, u3 = o2?g5:g3,
              u4 = o2?g6:g4, u5 = o2?g7:g5, u6 = o2?g8:g6, u7 = o2?g9:g7,
              u8 = o2?g10:g8;
        float f0 = o1?u1:u0, f1 = o1?u2:u1, f2 = o1?u3:u2, f3 = o1?u4:u3,
              f4 = o1?u5:u4, f5 = o1?u6:u5, f6 = o1?u7:u6, f7 = o1?u8:u7;
        uint4 vv;
        vv.x = pack2(f0, f1); vv.y = pack2(f2, f3);
        vv.z = pack2(f4, f5); vv.w = pack2(f6, f7);
        unsigned bo = ((unsigned)sr << 7) + ((((unsigned)su) << 4) ^ (((unsigned)(sr & 7)) << 4));
        *(uint4*)(sAraw[nbuf] + bo) = vv;
    };

    const bf16x8* wbase = (const bf16x8*)Wswz;
    auto loadW3 = [&](bf16x8 (&w)[3], int kg) {
        #pragma unroll
        for (int nt = 0; nt < 3; ++nt)
            w[nt] = wbase[(size_t)(kg * 24 + wid * 3 + nt) * 64 + l];
    };

    f32x4 acc[4][3];
    #pragma unroll
    for (int mi = 0; mi < 4; mi++)
        #pragma unroll
        for (int nt = 0; nt < 3; nt++) acc[mi][nt] = (f32x4){0.f, 0.f, 0.f, 0.f};
    bf16x8 wcur[3], wnxt[3], af[4];

    auto readAF = [&](int buf, int kk) {
        #pragma unroll
        for (int mi = 0; mi < 4; ++mi) {
            int row = c + mi * 16;
            unsigned bo = ((unsigned)row << 7) +
                ((((unsigned)kk << 6) + ((unsigned)g << 4)) ^ (((unsigned)(row & 7)) << 4));
            af[mi] = *(const bf16x8*)(sAraw[buf] + bo);
        }
    };
    auto M12 = [&](bf16x8 (&w)[3]) {
        __builtin_amdgcn_s_setprio(1);
        #pragma unroll
        for (int nt = 0; nt < 3; ++nt)
            #pragma unroll
            for (int mi = 0; mi < 4; ++mi)
                acc[mi][nt] = __builtin_amdgcn_mfma_f32_16x16x32_bf16(w[nt], af[mi], acc[mi][nt], 0, 0, 0);
        __builtin_amdgcn_s_setprio(0);
    };

    // ---- prologue ----
    stage_load(0);
    loadW3(wcur, 0);
    stage_finish(0);
    __syncthreads();

    // ---- chunk loop: 16 chunks of BK=64 (2 kg each) ----
    for (int ch = 0; ch < 16; ++ch) {
        const int buf = ch & 1;
        const int kg = ch * 2;
        loadW3(wnxt, kg + 1);                        // W first
        if (ch < 15) stage_load(ch + 1);             // stage after
        readAF(buf, 0); M12(wcur);
        if (ch < 15) loadW3(wcur, kg + 2);
        readAF(buf, 1); M12(wnxt);
        if (ch < 15) stage_finish(buf ^ 1);
        __syncthreads();
    }

    // ---- epilogue: hidden-units on reg axis -> cheap reduce ----
    float bv[12], wv[12];
    #pragma unroll
    for (int nt = 0; nt < 3; ++nt)
        #pragma unroll
        for (int r = 0; r < 4; ++r) {
            int nidx = (wid * 3 + nt) * 16 + g * 4 + r;
            bv[nt * 4 + r] = cb1[nidx];
            wv[nt * 4 + r] = cw2[nidx];
        }
    const int m_first = (wid * 3) >> 3, m_last = (wid * 3 + 2) >> 3;

    #pragma unroll
    for (int mi = 0; mi < 4; ++mi) {
        float s0 = 0.f, s1 = 0.f, s2 = 0.f;
        #pragma unroll
        for (int nt = 0; nt < 3; ++nt) {
            float p = 0.f;
            #pragma unroll
            for (int r = 0; r < 4; ++r) {
                float x = acc[mi][nt][r] + bv[nt * 4 + r];
                float h = fmaxf(x, 0.f) + __logf(1.f + __expf(-fabsf(x)));
                p += h * wv[nt * 4 + r];
            }
            int m = (wid * 3 + nt) >> 3;
            if (m == 0) s0 += p; else if (m == 1) s1 += p; else s2 += p;
        }
        auto red = [&](float v, int m) {
            v += __shfl_xor(v, 16);
            v += __shfl_xor(v, 32);
            if (l < 16) atomicAdd(&lds_s[m][mi * 16 + l], v);
        };
        if (m_first == 0) red(s0, 0);
        if (m_first <= 1 && m_last >= 1) red(s1, 1);
        if (m_last == 2) red(s2, 2);
    }
    __syncthreads();

    // ---- finalize per-row scalars in LDS ----
    if (tid < 64) {
        float s0 = lds_s[0][tid], s1 = lds_s[1][tid], s2 = lds_s[2][tid];
        lds_s[0][tid] = __expf(s0 + Eb2[0]);                      // Emod
        float mb = s1 + bb2[0];
        lds_s[1][tid] = mb * mb * (1.f / 40000.f);                // beta
        float mn = s2 + nb2[0];
        lds_s[2][tid] = __expf(mn * mn * (1.f / 40000.f));        // nuv
    }
    __syncthreads();

    // ---- fused scan: 2-row pairs (independent chains interleave) ----
    #pragma unroll
    for (int pi = 0; pi < 4; ++pi) {
        const int rA = wid * 8 + pi * 2, rB = rA + 1;
        const int bA = brow + rA, bB = brow + rB;
        float EmA = lds_s[0][rA], btA = lds_s[1][rA], nvA = lds_s[2][rA];
        float EmB = lds_s[0][rB], btB = lds_s[1][rB], nvB = lds_s[2][rB];
        float ccA = DT_ * btA, aA = 1.f - ccA;
        float ccB = DT_ * btB, aB = 1.f - ccB;

        size_t baA = (size_t)bA * T_ + (size_t)l * 8;
        size_t baB = (size_t)bB * T_ + (size_t)l * 8;
        float4 eA0 = *(const float4*)(e + baA),  eA1 = *(const float4*)(e + baA + 4);
        float4 eB0 = *(const float4*)(e + baB),  eB1 = *(const float4*)(e + baB + 4);
        float4 dA0 = *(const float4*)(ed + baA), dA1 = *(const float4*)(ed + baA + 4);
        float4 dB0 = *(const float4*)(ed + baB), dB1 = *(const float4*)(ed + baB + 4);
        float evA[8] = {eA0.x,eA0.y,eA0.z,eA0.w, eA1.x,eA1.y,eA1.z,eA1.w};
        float evB[8] = {eB0.x,eB0.y,eB0.z,eB0.w, eB1.x,eB1.y,eB1.z,eB1.w};
        float dvA[8] = {dA0.x,dA0.y,dA0.z,dA0.w, dA1.x,dA1.y,dA1.z,dA1.w};
        float dvB[8] = {dB0.x,dB0.y,dB0.z,dB0.w, dB1.x,dB1.y,dB1.z,dB1.w};

        float SA = 0.f, SB = 0.f;
        #pragma unroll
        for (int j = 0; j < 8; j++) { SA = aA * SA + evA[j]; SB = aB * SB + evB[j]; }
        float a2A = aA*aA, AA = (a2A*a2A)*(a2A*a2A);
        float a2B = aB*aB, AB = (a2B*a2B)*(a2B*a2B);

        #pragma unroll
        for (int d = 1; d < 64; d <<= 1) {
            float SuA = __shfl_up(SA, d), AuA = __shfl_up(AA, d);
            float SuB = __shfl_up(SB, d), AuB = __shfl_up(AB, d);
            if (l >= d) { SA = SuA * AA + SA; AA = AuA * AA;
                          SB = SuB * AB + SB; AB = AuB * AB; }
        }
        float SpA = __shfl_up(SA, 1), SpB = __shfl_up(SB, 1);
        float xiA = (l == 0) ? 0.f : ccA * SpA;
        float xiB = (l == 0) ? 0.f : ccB * SpB;

        float stA[8], xoA[8], stB[8], xoB[8];
        #pragma unroll
        for (int j = 0; j < 8; j++) {
            xoA[j] = xiA; xoB[j] = xiB;
            float qA = evA[j] - xiA, qB = evB[j] - xiB;
            stA[j] = EmA * evA[j] + qA + nvA * dvA[j];
            stB[j] = EmB * evB[j] + qB + nvB * dvB[j];
            xiA += ccA * qA; xiB += ccB * qB;
        }
        *(float4*)(stress + baA)     = (float4){stA[0],stA[1],stA[2],stA[3]};
        *(float4*)(stress + baA + 4) = (float4){stA[4],stA[5],stA[6],stA[7]};
        *(float4*)(stress + baB)     = (float4){stB[0],stB[1],stB[2],stB[3]};
        *(float4*)(stress + baB + 4) = (float4){stB[4],stB[5],stB[6],stB[7]};
        *(float4*)(xiout + baA)      = (float4){xoA[0],xoA[1],xoA[2],xoA[3]};
        *(float4*)(xiout + baA + 4)  = (float4){xoA[4],xoA[5],xoA[6],xoA[7]};
        *(float4*)(xiout + baB)      = (float4){xoB[0],xoB[1],xoB[2],xoB[3]};
        *(float4*)(xiout + baB + 4)  = (float4){xoB[4],xoB[5],xoB[6],xoB[7]};
    }
}

extern "C" void kernel_launch(void* const* d_in, const int* in_sizes, int n_in,
                              void* d_out, int out_size, void* d_ws, size_t ws_size,
                              hipStream_t stream) {
    const float* e   = (const float*)d_in[0];
    const float* ed  = (const float*)d_in[1];
    const float* E   = (const float*)d_in[2];
    const float* nu  = (const float*)d_in[3];
    const float* Ew1 = (const float*)d_in[4];
    const float* Eb1 = (const float*)d_in[5];
    const float* Ew2 = (const float*)d_in[6];
    const float* Eb2 = (const float*)d_in[7];
    const float* nw1 = (const float*)d_in[8];
    const float* nb1 = (const float*)d_in[9];
    const float* nw2 = (const float*)d_in[10];
    const float* nb2 = (const float*)d_in[11];
    const float* bw1 = (const float*)d_in[12];
    const float* bb1 = (const float*)d_in[13];
    const float* bw2 = (const float*)d_in[14];
    const float* bb2 = (const float*)d_in[15];

    int B = in_sizes[2] / M_;                       // 32768

    char* ws = (char*)d_ws;
    __hip_bfloat16* Wswz = (__hip_bfloat16*)ws;     // 786432 bytes

    float* stress = (float*)d_out;
    float* xiout  = stress + (size_t)B * T_;

    build_w<<<(1024 * 384 + 255) / 256, 256, 0, stream>>>(Ew1, bw1, nw1, Wswz);
    fused_all<<<B / 64, 512, 0, stream>>>(E, nu, Wswz, Eb1, bb1, nb1,
                                          Ew2, bw2, nw2, Eb2, bb2, nb2,
                                          e, ed, stress, xiout, B);
}